// Round 1
// baseline (1258.963 us; speedup 1.0000x reference)
//
#include <hip/hip_runtime.h>
#include <cstdint>
#include <math.h>

// XLA CPU (no fast-math) emits unfused mul/add for all HLO-level elementwise ops.
#pragma clang fp contract(off)

#define DEV __device__ __forceinline__

// ---------------------------------------------------------------- threefry2x32
struct U2 { unsigned a, b; };

DEV unsigned rotl32(unsigned v, int d) { return (v << d) | (v >> (32 - d)); }

DEV U2 tf2(unsigned k0, unsigned k1, unsigned x0, unsigned x1) {
  unsigned ks2 = k0 ^ k1 ^ 0x1BD11BDAu;
  x0 += k0; x1 += k1;
#define TFR(r) { x0 += x1; x1 = rotl32(x1, r); x1 ^= x0; }
  TFR(13) TFR(15) TFR(26) TFR(6)
  x0 += k1; x1 += ks2 + 1u;
  TFR(17) TFR(29) TFR(16) TFR(24)
  x0 += ks2; x1 += k0 + 2u;
  TFR(13) TFR(15) TFR(26) TFR(6)
  x0 += k0; x1 += k1 + 3u;
  TFR(17) TFR(29) TFR(16) TFR(24)
  x0 += k1; x1 += ks2 + 4u;
  TFR(13) TFR(15) TFR(26) TFR(6)
  x0 += ks2; x1 += k0 + 5u;
#undef TFR
  U2 r; r.a = x0; r.b = x1; return r;
}

// partitionable random_bits: element i -> out1 ^ out2 of block (0, i)
DEV unsigned rbits(unsigned k0, unsigned k1, unsigned idx) {
  U2 o = tf2(k0, k1, 0u, idx);
  return o.a ^ o.b;
}

DEV float u01(unsigned bits) {
  return __uint_as_float((bits >> 9) | 0x3F800000u) - 1.0f;
}

// ---------------------------------------------------------------- XLA CPU math
// Cephes/Eigen-style exp as in xla llvm_ir_runtime GenerateVF32Exp (unfused).
DEV float xla_exp(float xi) {
  float x = fminf(fmaxf(xi, -88.3762626647949f), 88.3762626647950f);
  float fx = floorf(x * 1.44269504088896341f + 0.5f);
  float tmp = 0.693359375f * fx;
  float z = -2.12194440e-4f * fx;
  x = x - tmp;
  x = x - z;
  z = x * x;
  float y = 1.9875691500e-4f * x + 1.3981999507e-3f;
  y = y * x + 8.3334519073e-3f;
  y = y * x + 4.1665795894e-2f;
  y = y * x + 1.6666665459e-1f;
  y = y * x + 5.0000001201e-1f;
  y = y * z + x;
  y = y + 1.0f;
  int n = (int)fx;
  float two_n = __uint_as_float((unsigned)(n + 127) << 23);
  return fmaxf(y * two_n, xi);
}

// Cephes/Eigen-style log as in GenerateVF32Log (3-way split polynomial).
DEV float xla_log(float xi) {
  float xc = fmaxf(xi, 1.17549435082228751e-38f); // flush denormals
  unsigned bits = __float_as_uint(xc);
  float e = (float)((int)(bits >> 23) - 126);
  float m = __uint_as_float((bits & 0x007FFFFFu) | 0x3F000000u); // [0.5,1)
  bool msk = m < 0.707106781186547524f;
  float tmp = msk ? m : 0.0f;
  float em  = msk ? 1.0f : 0.0f;
  m = m - 1.0f;
  e = e - em;
  m = m + tmp;
  float z  = m * m;
  float x3 = z * m;
  float y0 = 7.0376836292e-2f  * m + -1.1514610310e-1f;
  float y1 = -1.2420140846e-1f * m + 1.4249322787e-1f;
  float y2 = 2.0000714765e-1f  * m + -2.4999993993e-1f;
  y0 = y0 * m + 1.1676998740e-1f;
  y1 = y1 * m + -1.6668057665e-1f;
  y2 = y2 * m + 3.3333331174e-1f;
  y0 = y0 * x3 + y1;
  y0 = y0 * x3 + y2;
  y0 = y0 * x3;
  y0 = -2.12194440e-4f * e + y0;
  y0 = y0 - 0.5f * z;
  float r = m + y0;
  r = 0.693359375f * e + r;
  if (!(xi > 0.0f)) r = (xi == 0.0f) ? -__builtin_inff() : __builtin_nanf("");
  if (xi == __builtin_inff()) r = __builtin_inff();
  return r;
}

// XLA rational tanh (GenerateVF32Tanh): |x|<4e-4 -> x, clamp +-9.
DEV float xla_tanh(float x) {
  float xc = fminf(fmaxf(x, -9.0f), 9.0f);
  float x2 = xc * xc;
  float p = x2 * -2.76076847742355e-16f + 2.00018790482477e-13f;
  p = p * x2 + -8.60467152213735e-11f;
  p = p * x2 + 5.12229709037114e-08f;
  p = p * x2 + 1.48572235717979e-05f;
  p = p * x2 + 6.37261928875436e-04f;
  p = p * x2 + 4.89352455891786e-03f;
  p = xc * p;
  float q = x2 * 1.19825839466702e-06f + 1.18534705686654e-04f;
  q = q * x2 + 2.26843463243900e-03f;
  q = q * x2 + 4.89352518554385e-03f;
  float r = p / q;
  return (fabsf(x) < 0.0004f) ? x : r;
}

DEV float sqrt_cr(float x) { return (float)sqrt((double)x); }

// XLA elemental log1p: |x| < 1e-4 -> x*(1 - 0.5x), else log(1+x)
DEV float xla_log1p(float x) {
  float fl = xla_log(x + 1.0f);
  float fs = ((-0.5f) * x + 1.0f) * x;
  return (fabsf(x) < 1e-4f) ? fs : fl;
}

// jax.nn.softplus = logaddexp(x,0) = max(x,0) + log1p(exp(-|x|))
DEV float softplus_ref(float x) {
  float amax = fmaxf(x, 0.0f);
  return amax + xla_log1p(xla_exp(-fabsf(x)));
}

// XLA ErfInv32 (Giles polynomials, unfused poly eval)
DEV float xla_erfinv(float x) {
  float w = -xla_log1p(-(x * x));
  bool lt = w < 5.0f;
  float wa = lt ? (w - 2.5f) : (sqrt_cr(w) - 3.0f);
  float p;
  if (lt) {
    p = 2.81022636e-08f;
    p = p * wa + 3.43273939e-07f;
    p = p * wa + -3.5233877e-06f;
    p = p * wa + -4.39150654e-06f;
    p = p * wa + 0.00021858087f;
    p = p * wa + -0.00125372503f;
    p = p * wa + -0.00417768164f;
    p = p * wa + 0.246640727f;
    p = p * wa + 1.50140941f;
  } else {
    p = -0.000200214257f;
    p = p * wa + 0.000100950558f;
    p = p * wa + 0.00134934322f;
    p = p * wa + -0.00367342844f;
    p = p * wa + 0.00573950773f;
    p = p * wa + -0.0076224613f;
    p = p * wa + 0.00943887047f;
    p = p * wa + 1.00167406f;
    p = p * wa + 2.83297682f;
  }
  return p * x;
}

// pow(x, -1/1.2) with f32 exponent semantics; glibc powf is correctly rounded,
// emulate via double pow.
DEV float powm(float x) {
  const double e = (double)((float)(-1.0 / 1.2));
  return (float)pow((double)x, e);
}

// ---------------------------------------------------------------- constants
#define Bn 32
#define Tn 64
#define Dn 32
#define Sn 64
#define Jn 16
#define SIG2F  0.0025000000000000005f
#define RATE1F 13.207443270509278f
#define LO_N  -0.99999994039535522f
#define SQRT2F 1.4142135623730951f

// ---------------------------------------------------------------- phi precompute
// A[t][d] = -softplus(out[:32]), B[t][d] = out[32:], dscale[d] = softplus(diff_log)
__global__ void __launch_bounds__(64) phi_kernel(
    const float* __restrict__ tseq,
    const float* __restrict__ pW1, const float* __restrict__ pb1,
    const float* __restrict__ pW2, const float* __restrict__ pb2,
    const float* __restrict__ pW3, const float* __restrict__ pb3,
    const float* __restrict__ diff_log, float* __restrict__ ws) {
  __shared__ float h1[64], h2[64];
  int t = blockIdx.x, w = threadIdx.x;
  float tv = tseq[t];
  h1[w] = xla_tanh(tv * pW1[w] + pb1[w]);
  __syncthreads();
  float acc = 0.0f;
  for (int k = 0; k < 64; ++k) acc = fmaf(h1[k], pW2[k * 64 + w], acc);
  acc = acc + pb2[w];
  h2[w] = xla_tanh(acc);
  __syncthreads();
  acc = 0.0f;
  for (int k = 0; k < 64; ++k) acc = fmaf(h2[k], pW3[k * 64 + w], acc);
  acc = acc + pb3[w];
  if (w < 32) ws[t * 32 + w] = -softplus_ref(acc);
  else        ws[2048 + t * 32 + (w - 32)] = acc;
  if (t == 0 && w < 32) ws[4096 + w] = softplus_ref(diff_log[w]);
}

// ---------------------------------------------------------------- main sim
__global__ void __launch_bounds__(512) sim_kernel(
    const float* __restrict__ state_init, const float* __restrict__ tseq,
    const float* __restrict__ gW1, const float* __restrict__ gb1,
    const float* __restrict__ gW2, const float* __restrict__ gb2,
    const float* __restrict__ gW3, const float* __restrict__ gb3,
    const float* __restrict__ ws, float* __restrict__ out) {
  const int b = blockIdx.x;
  const int tid = threadIdx.x;

  __shared__ float sW1[33 * 64], sB1[64], sW2[64 * 64], sB2[64], sW3[64 * 32], sB3[32];
  __shared__ float sTseq[64];
  __shared__ float sX[32], sK1[32], sA[32], sMb[32], sDrift[32], sDs[32];
  __shared__ int   sNj[32];
  __shared__ float sH1[64], sH2[64];
  __shared__ float sTilt[32 * 65];   // padded rows: bank-conflict-free column sums
  __shared__ float sCond[512];
  __shared__ unsigned sChain[8][2], sKp[8][2], sKa[8][2];

  for (int i = tid; i < 33 * 64; i += 512) sW1[i] = gW1[i];
  for (int i = tid; i < 64 * 64; i += 512) sW2[i] = gW2[i];
  for (int i = tid; i < 64 * 32; i += 512) sW3[i] = gW3[i];
  if (tid < 64) { sB1[tid] = gb1[tid]; sB2[tid] = gb2[tid]; sTseq[tid] = tseq[tid]; }
  if (tid < 32) { sB3[tid] = gb3[tid]; sX[tid] = state_init[b * 32 + tid]; sDs[tid] = ws[4096 + tid]; }
  __syncthreads();

  unsigned key0 = 0u, key1 = 42u;   // jax.random.key(42)
  float past_t = sTseq[0];

  for (int ti = 0; ti < Tn; ++ti) {
    float t = sTseq[ti];
    float dt = t - past_t;

    // key, k_stab, k_pois, k_rej, k_gauss = split(key, 5)  (foldlike children)
    U2 c0 = tf2(key0, key1, 0u, 0u);
    U2 c1 = tf2(key0, key1, 0u, 1u);
    U2 c2 = tf2(key0, key1, 0u, 2u);
    U2 c3 = tf2(key0, key1, 0u, 3u);
    U2 c4 = tf2(key0, key1, 0u, 4u);
    key0 = c0.a; key1 = c0.b;
    unsigned ks0 = c1.a, ks1 = c1.b;
    unsigned kp0 = c2.a, kp1 = c2.b;
    unsigned kr0 = c3.a, kr1 = c3.b;
    unsigned kg0 = c4.a, kg1 = c4.b;

    // ---- Phase 1: drift MLP (old X), K1, Mb
    if (tid < 64) {
      float acc = 0.0f;
      acc = fmaf(t, sW1[tid], acc);
      for (int k = 1; k < 33; ++k) acc = fmaf(sX[k - 1], sW1[k * 64 + tid], acc);
      acc = acc + sB1[tid];
      sH1[tid] = xla_tanh(acc);
    }
    __syncthreads();
    if (tid < 64) {
      float acc = 0.0f;
      for (int k = 0; k < 64; ++k) acc = fmaf(sH1[k], sW2[k * 64 + tid], acc);
      acc = acc + sB2[tid];
      sH2[tid] = xla_tanh(acc);
    }
    __syncthreads();
    if (tid < 32) {
      float acc = 0.0f;
      for (int k = 0; k < 64; ++k) acc = fmaf(sH2[k], sW3[k * 32 + tid], acc);
      acc = acc + sB3[tid];
      sDrift[tid] = acc;
      float A  = ws[ti * 32 + tid];
      float Bv = ws[2048 + ti * 32 + tid];
      sA[tid] = A;
      float K1 = (2.0f * A) * sX[tid] + Bv;
      sK1[tid] = K1;
      sMb[tid] = xla_exp((-(K1 * K1)) / (4.0f * A));
    }
    __syncthreads();

    // ---- Phase 2: tilt_w over (S,D)
    for (int e = tid; e < Sn * Dn; e += 512) {
      int d = e & 31;
      float u = u01(rbits(ks0, ks1, (unsigned)(b * 2048 + e)));
      float raw = 0.1f * powm(1.0f - u);
      float scaled = sDs[d] * raw;
      float quad = sA[d] * (scaled * scaled);
      float lin = sK1[d] * scaled;
      float lh = 80.0f * xla_tanh((quad + lin) / 80.0f);
      float nh = 80.0f * xla_tanh((quad - lin) / 80.0f);
      sTilt[d * 65 + (e >> 5)] = xla_exp(lh) + xla_exp(nh);
    }
    __syncthreads();

    // ---- Phase 3a: per-d 95% quantile clip (wave bitonic sort)
    {
      int wv = tid >> 6, lane = tid & 63;
      for (int d = wv; d < 32; d += 8) {
        float vo = sTilt[d * 65 + lane];
        float v = vo;
        for (int k = 2; k <= 64; k <<= 1)
          for (int j = k >> 1; j > 0; j >>= 1) {
            float o = __shfl_xor(v, j, 64);
            bool keepmin = (((lane & j) == 0) == ((lane & k) == 0));
            v = keepmin ? fminf(v, o) : fmaxf(v, o);
          }
        float s59 = __shfl(v, 59, 64);
        float s60 = __shfl(v, 60, 64);
        float qv = 0.95f * 63.0f;
        float hw = qv - 59.0f;
        float lw = 1.0f - hw;
        float tq = s59 * lw + s60 * hw;
        sTilt[d * 65 + lane] = fminf(vo, tq);
      }
    }
    __syncthreads();

    // ---- Phase 3b: mean -> lam -> Knuth Poisson; rejection key chain on spare wave
    if (tid < 32) {
      int d = tid;
      float sum = 0.0f;
      for (int s = 0; s < 64; ++s) sum = sum + sTilt[d * 65 + s];
      float tilt = sum / 64.0f;
      float lam = (tilt * RATE1F) * dt;
      int n = 0;
      if (lam != 0.0f) {
        unsigned r0 = kp0, r1 = kp1;
        float log_prod = 0.0f;
        int k = 0;
        while (log_prod > -lam && k < 256) {
          k += 1;
          U2 sub = tf2(r0, r1, 0u, 1u);   // subkey = child 1
          U2 nxt = tf2(r0, r1, 0u, 0u);   // rng    = child 0
          r0 = nxt.a; r1 = nxt.b;
          float u = u01(rbits(sub.a, sub.b, (unsigned)(b * 32 + d)));
          log_prod = log_prod + xla_log(u);
        }
        n = k - 1;
      }
      sNj[d] = n;
    } else if (tid == 64) {
      unsigned a0 = kr0, a1 = kr1;
      for (int a = 0; a < 8; ++a) {
        sChain[a][0] = a0; sChain[a][1] = a1;
        U2 nk = tf2(a0, a1, 0u, 0u);      // carry key = child 0
        a0 = nk.a; a1 = nk.b;
      }
    }
    __syncthreads();
    if (tid < 16) {
      int a = tid & 7;
      U2 kk = tf2(sChain[a][0], sChain[a][1], 0u, (tid < 8) ? 1u : 2u); // kp=c1, ka=c2
      if (tid < 8) { sKp[a][0] = kk.a; sKp[a][1] = kk.b; }
      else         { sKa[a][0] = kk.a; sKa[a][1] = kk.b; }
    }
    __syncthreads();

    // ---- Phase 4+5: rejection sampling (8 attempts) + conditional gaussian
    {
      int d = tid & 31;
      unsigned i = (unsigned)(b * 512 + tid);
      float A = sA[d], K1 = sK1[d], Mb = sMb[d];
      float K1sq = K1 * K1;
      float r = 0.1f;
      bool accd = false;
      for (int a = 0; a < 8; ++a) {
        if (!accd) {
          float u1 = u01(rbits(sKp[a][0], sKp[a][1], i));
          float rp = 0.1f * powm(1.0f - u1);
          float rp2 = rp * rp;
          float den = fmaxf(1.0f - ((2.0f * A) * rp2) * SIG2F, 1e-6f);
          float Cv = xla_exp(((K1sq * rp2) * SIG2F) / (2.0f * den)) / sqrt_cr(den);
          float p = fminf(Cv / Mb, 1.0f);
          float u2 = u01(rbits(sKa[a][0], sKa[a][1], i));
          if (u2 < p) { r = rp; accd = true; }
        }
      }
      float fz = u01(rbits(kg0, kg1, i));
      float un = fmaxf(LO_N, fz * 2.0f + LO_N);
      float z = SQRT2F * xla_erfinv(un);
      float t2 = (2.0f * (r * r)) * SIG2F;
      float K2 = A - 1.0f / t2;
      float K2s = (K2 < -1e-6f) ? K2 : -1e-6f;
      float mean = (-K1) / (2.0f * K2s);
      float var = (-1.0f) / (2.0f * K2s);
      float cond = mean + sqrt_cr(var) * z;
      bool mk = (tid >> 5) < sNj[d];
      sCond[tid] = cond * (mk ? 1.0f : 0.0f);
    }
    __syncthreads();

    // ---- Phase 6: aggregate jumps, clip, update state, write output
    if (tid < 32) {
      int d = tid;
      float soj = 0.0f;
      for (int j = 0; j < 16; ++j) soj = soj + sCond[j * 32 + d];
      soj = 2.5f * xla_tanh(soj / 2.5f);
      float Xn = (sX[d] + sDrift[d] * dt) + sDs[d] * soj;
      sX[d] = Xn;
      out[ti * 1024 + b * 32 + d] = Xn;
    }
    __syncthreads();
    past_t = t;
  }
}

// ---------------------------------------------------------------- launch
extern "C" void kernel_launch(void* const* d_in, const int* in_sizes, int n_in,
                              void* d_out, int out_size, void* d_ws, size_t ws_size,
                              hipStream_t stream) {
  const float* state_init = (const float*)d_in[0];
  const float* tseq       = (const float*)d_in[1];
  const float* dW1        = (const float*)d_in[2];
  const float* db1        = (const float*)d_in[3];
  const float* dW2        = (const float*)d_in[4];
  const float* db2        = (const float*)d_in[5];
  const float* dW3        = (const float*)d_in[6];
  const float* db3        = (const float*)d_in[7];
  const float* diff_log   = (const float*)d_in[8];
  const float* pW1        = (const float*)d_in[9];
  const float* pb1        = (const float*)d_in[10];
  const float* pW2        = (const float*)d_in[11];
  const float* pb2        = (const float*)d_in[12];
  const float* pW3        = (const float*)d_in[13];
  const float* pb3        = (const float*)d_in[14];
  float* ws = (float*)d_ws;

  phi_kernel<<<64, 64, 0, stream>>>(tseq, pW1, pb1, pW2, pb2, pW3, pb3, diff_log, ws);
  sim_kernel<<<32, 512, 0, stream>>>(state_init, tseq, dW1, db1, dW2, db2, dW3, db3,
                                     ws, (float*)d_out);
}

// Round 2
// 1040.311 us; speedup vs baseline: 1.2102x; 1.2102x over previous
//
#include <hip/hip_runtime.h>
#include <cstdint>
#include <math.h>

// XLA CPU (no fast-math) emits unfused mul/add for all HLO-level elementwise ops.
#pragma clang fp contract(off)

#define DEV __device__ __forceinline__

// ---------------------------------------------------------------- threefry2x32
struct U2 { unsigned a, b; };

DEV unsigned rotl32(unsigned v, int d) { return (v << d) | (v >> (32 - d)); }

DEV U2 tf2(unsigned k0, unsigned k1, unsigned x0, unsigned x1) {
  unsigned ks2 = k0 ^ k1 ^ 0x1BD11BDAu;
  x0 += k0; x1 += k1;
#define TFR(r) { x0 += x1; x1 = rotl32(x1, r); x1 ^= x0; }
  TFR(13) TFR(15) TFR(26) TFR(6)
  x0 += k1; x1 += ks2 + 1u;
  TFR(17) TFR(29) TFR(16) TFR(24)
  x0 += ks2; x1 += k0 + 2u;
  TFR(13) TFR(15) TFR(26) TFR(6)
  x0 += k0; x1 += k1 + 3u;
  TFR(17) TFR(29) TFR(16) TFR(24)
  x0 += k1; x1 += ks2 + 4u;
  TFR(13) TFR(15) TFR(26) TFR(6)
  x0 += ks2; x1 += k0 + 5u;
#undef TFR
  U2 r; r.a = x0; r.b = x1; return r;
}

// partitionable random_bits: element i -> out1 ^ out2 of block (0, i)
DEV unsigned rbits(unsigned k0, unsigned k1, unsigned idx) {
  U2 o = tf2(k0, k1, 0u, idx);
  return o.a ^ o.b;
}

DEV float u01(unsigned bits) {
  return __uint_as_float((bits >> 9) | 0x3F800000u) - 1.0f;
}

// ---------------------------------------------------------------- XLA CPU math
DEV float xla_exp(float xi) {
  float x = fminf(fmaxf(xi, -88.3762626647949f), 88.3762626647950f);
  float fx = floorf(x * 1.44269504088896341f + 0.5f);
  float tmp = 0.693359375f * fx;
  float z = -2.12194440e-4f * fx;
  x = x - tmp;
  x = x - z;
  z = x * x;
  float y = 1.9875691500e-4f * x + 1.3981999507e-3f;
  y = y * x + 8.3334519073e-3f;
  y = y * x + 4.1665795894e-2f;
  y = y * x + 1.6666665459e-1f;
  y = y * x + 5.0000001201e-1f;
  y = y * z + x;
  y = y + 1.0f;
  int n = (int)fx;
  float two_n = __uint_as_float((unsigned)(n + 127) << 23);
  return fmaxf(y * two_n, xi);
}

DEV float xla_log(float xi) {
  float xc = fmaxf(xi, 1.17549435082228751e-38f);
  unsigned bits = __float_as_uint(xc);
  float e = (float)((int)(bits >> 23) - 126);
  float m = __uint_as_float((bits & 0x007FFFFFu) | 0x3F000000u);
  bool msk = m < 0.707106781186547524f;
  float tmp = msk ? m : 0.0f;
  float em  = msk ? 1.0f : 0.0f;
  m = m - 1.0f;
  e = e - em;
  m = m + tmp;
  float z  = m * m;
  float x3 = z * m;
  float y0 = 7.0376836292e-2f  * m + -1.1514610310e-1f;
  float y1 = -1.2420140846e-1f * m + 1.4249322787e-1f;
  float y2 = 2.0000714765e-1f  * m + -2.4999993993e-1f;
  y0 = y0 * m + 1.1676998740e-1f;
  y1 = y1 * m + -1.6668057665e-1f;
  y2 = y2 * m + 3.3333331174e-1f;
  y0 = y0 * x3 + y1;
  y0 = y0 * x3 + y2;
  y0 = y0 * x3;
  y0 = -2.12194440e-4f * e + y0;
  y0 = y0 - 0.5f * z;
  float r = m + y0;
  r = 0.693359375f * e + r;
  if (!(xi > 0.0f)) r = (xi == 0.0f) ? -__builtin_inff() : __builtin_nanf("");
  if (xi == __builtin_inff()) r = __builtin_inff();
  return r;
}

DEV float xla_tanh(float x) {
  float xc = fminf(fmaxf(x, -9.0f), 9.0f);
  float x2 = xc * xc;
  float p = x2 * -2.76076847742355e-16f + 2.00018790482477e-13f;
  p = p * x2 + -8.60467152213735e-11f;
  p = p * x2 + 5.12229709037114e-08f;
  p = p * x2 + 1.48572235717979e-05f;
  p = p * x2 + 6.37261928875436e-04f;
  p = p * x2 + 4.89352455891786e-03f;
  p = xc * p;
  float q = x2 * 1.19825839466702e-06f + 1.18534705686654e-04f;
  q = q * x2 + 2.26843463243900e-03f;
  q = q * x2 + 4.89352518554385e-03f;
  float r = p / q;
  return (fabsf(x) < 0.0004f) ? x : r;
}

DEV float sqrt_cr(float x) { return (float)sqrt((double)x); }

DEV float xla_log1p(float x) {
  float fl = xla_log(x + 1.0f);
  float fs = ((-0.5f) * x + 1.0f) * x;
  return (fabsf(x) < 1e-4f) ? fs : fl;
}

DEV float softplus_ref(float x) {
  float amax = fmaxf(x, 0.0f);
  return amax + xla_log1p(xla_exp(-fabsf(x)));
}

DEV float xla_erfinv(float x) {
  float w = -xla_log1p(-(x * x));
  bool lt = w < 5.0f;
  float wa = lt ? (w - 2.5f) : (sqrt_cr(w) - 3.0f);
  float p;
  if (lt) {
    p = 2.81022636e-08f;
    p = p * wa + 3.43273939e-07f;
    p = p * wa + -3.5233877e-06f;
    p = p * wa + -4.39150654e-06f;
    p = p * wa + 0.00021858087f;
    p = p * wa + -0.00125372503f;
    p = p * wa + -0.00417768164f;
    p = p * wa + 0.246640727f;
    p = p * wa + 1.50140941f;
  } else {
    p = -0.000200214257f;
    p = p * wa + 0.000100950558f;
    p = p * wa + 0.00134934322f;
    p = p * wa + -0.00367342844f;
    p = p * wa + 0.00573950773f;
    p = p * wa + -0.0076224613f;
    p = p * wa + 0.00943887047f;
    p = p * wa + 1.00167406f;
    p = p * wa + 2.83297682f;
  }
  return p * x;
}

DEV float powm(float x) {
  const double e = (double)((float)(-1.0 / 1.2));
  return (float)pow((double)x, e);
}

// ---------------------------------------------------------------- constants
#define Bn 32
#define Tn 64
#define Dn 32
#define Sn 64
#define Jn 16
#define SIG2F  0.0025000000000000005f
#define RATE1F 13.207443270509278f
#define LO_N  -0.99999994039535522f
#define SQRT2F 1.4142135623730951f

// ws layout (float / uint indices)
#define OFF_A    0          // 2048
#define OFF_B    2048       // 2048
#define OFF_DS   4096       // 32
#define OFF_KEYS 4128       // 64*8 uints: ks0,ks1,kp0,kp1,kr0,kr1,kg0,kg1
#define OFF_KA   4640       // 64*8*2 uints
#define OFF_KP   5664       // 64*8*2 uints
#define OFF_SUB  6688       // 64*17*2 uints
#define OFF_RAW  16384      // 4194304 floats
#define OFF_RP   4210688    // 8388608 floats
#define OFF_LK   12599296   // 1114112 floats
#define WS_FLOATS_NEEDED 13713408
#define NRAW 4194304
#define NTOT 12582912

// ---------------------------------------------------------------- key tables
__global__ void __launch_bounds__(64) key_kernel(unsigned* __restrict__ wsu) {
  __shared__ unsigned lk[64][2];
  int t = threadIdx.x;
  if (t == 0) {
    unsigned k0 = 0u, k1 = 42u;   // jax.random.key(42)
    for (int i = 0; i < 64; ++i) {
      lk[i][0] = k0; lk[i][1] = k1;
      U2 c0 = tf2(k0, k1, 0u, 0u);
      k0 = c0.a; k1 = c0.b;
    }
  }
  __syncthreads();
  unsigned k0 = lk[t][0], k1 = lk[t][1];
  U2 c1 = tf2(k0, k1, 0u, 1u);  // k_stab
  U2 c2 = tf2(k0, k1, 0u, 2u);  // k_pois
  U2 c3 = tf2(k0, k1, 0u, 3u);  // k_rej
  U2 c4 = tf2(k0, k1, 0u, 4u);  // k_gauss
  wsu[OFF_KEYS + t * 8 + 0] = c1.a; wsu[OFF_KEYS + t * 8 + 1] = c1.b;
  wsu[OFF_KEYS + t * 8 + 2] = c2.a; wsu[OFF_KEYS + t * 8 + 3] = c2.b;
  wsu[OFF_KEYS + t * 8 + 4] = c3.a; wsu[OFF_KEYS + t * 8 + 5] = c3.b;
  wsu[OFF_KEYS + t * 8 + 6] = c4.a; wsu[OFF_KEYS + t * 8 + 7] = c4.b;
  // rejection chain: per attempt kp=c1, ka=c2, carry=c0
  unsigned a0 = c3.a, a1 = c3.b;
  for (int a = 0; a < 8; ++a) {
    U2 kp = tf2(a0, a1, 0u, 1u);
    U2 ka = tf2(a0, a1, 0u, 2u);
    U2 nx = tf2(a0, a1, 0u, 0u);
    wsu[OFF_KP + (t * 8 + a) * 2 + 0] = kp.a; wsu[OFF_KP + (t * 8 + a) * 2 + 1] = kp.b;
    wsu[OFF_KA + (t * 8 + a) * 2 + 0] = ka.a; wsu[OFF_KA + (t * 8 + a) * 2 + 1] = ka.b;
    a0 = nx.a; a1 = nx.b;
  }
  // poisson per-iteration subkeys: sub=c1, carry=c0
  unsigned r0 = c2.a, r1 = c2.b;
  for (int k = 0; k < 17; ++k) {
    U2 sub = tf2(r0, r1, 0u, 1u);
    U2 nx  = tf2(r0, r1, 0u, 0u);
    wsu[OFF_SUB + (t * 17 + k) * 2 + 0] = sub.a; wsu[OFF_SUB + (t * 17 + k) * 2 + 1] = sub.b;
    r0 = nx.a; r1 = nx.b;
  }
}

// ---------------------------------------------------------------- heavy pow precompute
__global__ void __launch_bounds__(256) stable_kernel(const unsigned* __restrict__ wsu,
                                                     float* __restrict__ ws) {
  int stride = gridDim.x * blockDim.x;
  for (int idx = blockIdx.x * blockDim.x + threadIdx.x; idx < NTOT; idx += stride) {
    if (idx < NRAW) {
      // raw[t][b][e]: t=idx>>16, b=(idx>>11)&31, e=idx&2047
      int t = idx >> 16;
      int b = (idx >> 11) & 31;
      int e = idx & 2047;
      unsigned k0 = wsu[OFF_KEYS + t * 8 + 0], k1 = wsu[OFF_KEYS + t * 8 + 1];
      float u = u01(rbits(k0, k1, (unsigned)(b * 2048 + e)));
      ws[OFF_RAW + idx] = 0.1f * powm(1.0f - u);
    } else {
      // rp[t][b][jd][a]: i2>>17, (i2>>12)&31, (i2>>3)&511, i2&7
      int i2 = idx - NRAW;
      int t = i2 >> 17;
      int b = (i2 >> 12) & 31;
      int jd = (i2 >> 3) & 511;
      int a = i2 & 7;
      unsigned k0 = wsu[OFF_KP + (t * 8 + a) * 2], k1 = wsu[OFF_KP + (t * 8 + a) * 2 + 1];
      float u1 = u01(rbits(k0, k1, (unsigned)(b * 512 + jd)));
      ws[OFF_RP + i2] = 0.1f * powm(1.0f - u1);
    }
  }
}

// Poisson log-uniform prefix sums L_k, k=1..17
__global__ void __launch_bounds__(256) lk_kernel(const unsigned* __restrict__ wsu,
                                                 float* __restrict__ ws) {
  int idx = blockIdx.x * 256 + threadIdx.x;   // 65536 = 64*32*32
  int t = idx >> 10;
  int b = (idx >> 5) & 31;
  int d = idx & 31;
  float L = 0.0f;
  for (int k = 0; k < 17; ++k) {
    unsigned s0 = wsu[OFF_SUB + (t * 17 + k) * 2], s1 = wsu[OFF_SUB + (t * 17 + k) * 2 + 1];
    float u = u01(rbits(s0, s1, (unsigned)(b * 32 + d)));
    L = L + xla_log(u);
    ws[OFF_LK + ((t * 32 + b) * 17 + k) * 32 + d] = L;
  }
}

// ---------------------------------------------------------------- phi precompute
__global__ void __launch_bounds__(64) phi_kernel(
    const float* __restrict__ tseq,
    const float* __restrict__ pW1, const float* __restrict__ pb1,
    const float* __restrict__ pW2, const float* __restrict__ pb2,
    const float* __restrict__ pW3, const float* __restrict__ pb3,
    const float* __restrict__ diff_log, float* __restrict__ ws) {
  __shared__ float h1[64], h2[64];
  int t = blockIdx.x, w = threadIdx.x;
  float tv = tseq[t];
  h1[w] = xla_tanh(tv * pW1[w] + pb1[w]);
  __syncthreads();
  float acc = 0.0f;
  for (int k = 0; k < 64; ++k) acc = fmaf(h1[k], pW2[k * 64 + w], acc);
  acc = acc + pb2[w];
  h2[w] = xla_tanh(acc);
  __syncthreads();
  acc = 0.0f;
  for (int k = 0; k < 64; ++k) acc = fmaf(h2[k], pW3[k * 64 + w], acc);
  acc = acc + pb3[w];
  if (w < 32) ws[OFF_A + t * 32 + w] = -softplus_ref(acc);
  else        ws[OFF_B + t * 32 + (w - 32)] = acc;
  if (t == 0 && w < 32) ws[OFF_DS + w] = softplus_ref(diff_log[w]);
}

// ---------------------------------------------------------------- main sim
template <bool PRE>
__global__ void __launch_bounds__(1024) sim_kernel(
    const float* __restrict__ state_init, const float* __restrict__ tseq,
    const float* __restrict__ gW1, const float* __restrict__ gb1,
    const float* __restrict__ gW2, const float* __restrict__ gb2,
    const float* __restrict__ gW3, const float* __restrict__ gb3,
    const float* __restrict__ ws, const unsigned* __restrict__ wsu,
    float* __restrict__ out) {
  const int b = blockIdx.x;
  const int tid = threadIdx.x;

  __shared__ float sW1[33 * 64], sB1[64], sW2[64 * 64], sB2[64], sW3[64 * 32], sB3[32];
  __shared__ float sTseq[64];
  __shared__ float sX[32], sK1[32], sA[32], sMb[32], sDrift[32], sDs[32];
  __shared__ int   sNj[32];
  __shared__ float sH1[64], sH2[64];
  __shared__ float sTilt[32 * 65];
  __shared__ float sCond[512];
  __shared__ float sRp[4096];
  __shared__ unsigned char sFlag[4096];
  __shared__ unsigned sKeyStep[8], sKaF[16], sKpF[16], sSubF[34];

  for (int i = tid; i < 33 * 64; i += 1024) sW1[i] = gW1[i];
  for (int i = tid; i < 64 * 64; i += 1024) sW2[i] = gW2[i];
  for (int i = tid; i < 64 * 32; i += 1024) sW3[i] = gW3[i];
  if (tid < 64) { sB1[tid] = gb1[tid]; sB2[tid] = gb2[tid]; sTseq[tid] = tseq[tid]; }
  if (tid < 32) { sB3[tid] = gb3[tid]; sX[tid] = state_init[b * 32 + tid]; sDs[tid] = ws[OFF_DS + tid]; }
  __syncthreads();

  float past_t = sTseq[0];

  for (int ti = 0; ti < Tn; ++ti) {
    float t = sTseq[ti];
    float dt = t - past_t;

    // ---- step-top prefetch (all addresses data-independent)
    float pRaw0 = 0.0f, pRaw1 = 0.0f, pRp[4] = {0, 0, 0, 0};
    float pLk[17];
    float pA = 0.0f, pBc = 0.0f;
    if (PRE) {
      int rawbase = (ti * 32 + b) * 2048;
      pRaw0 = ws[OFF_RAW + rawbase + tid];
      pRaw1 = ws[OFF_RAW + rawbase + tid + 1024];
      int rpbase = (ti * 32 + b) * 4096;
#pragma unroll
      for (int q = 0; q < 4; ++q) pRp[q] = ws[OFF_RP + rpbase + tid + q * 1024];
    }
    if (tid < 32) {
      if (PRE) {
#pragma unroll
        for (int k = 0; k < 17; ++k) pLk[k] = ws[OFF_LK + ((ti * 32 + b) * 17 + k) * 32 + tid];
      }
      pA  = ws[OFF_A + ti * 32 + tid];
      pBc = ws[OFF_B + ti * 32 + tid];
    }
    if (tid < 8)  sKeyStep[tid] = wsu[OFF_KEYS + ti * 8 + tid];
    if (tid >= 8  && tid < 24) sKaF[tid - 8]  = wsu[OFF_KA + ti * 16 + (tid - 8)];
    if (tid >= 24 && tid < 40) sKpF[tid - 24] = wsu[OFF_KP + ti * 16 + (tid - 24)];
    if (tid >= 40 && tid < 74) sSubF[tid - 40] = wsu[OFF_SUB + ti * 34 + (tid - 40)];

    // ---- Phase 1: drift MLP (old X), K1, Mb
    if (tid < 64) {
      float acc = 0.0f;
      acc = fmaf(t, sW1[tid], acc);
      for (int k = 1; k < 33; ++k) acc = fmaf(sX[k - 1], sW1[k * 64 + tid], acc);
      acc = acc + sB1[tid];
      sH1[tid] = xla_tanh(acc);
    }
    __syncthreads();
    if (tid < 64) {
      float acc = 0.0f;
      for (int k = 0; k < 64; ++k) acc = fmaf(sH1[k], sW2[k * 64 + tid], acc);
      acc = acc + sB2[tid];
      sH2[tid] = xla_tanh(acc);
    }
    __syncthreads();
    if (tid < 32) {
      float acc = 0.0f;
      for (int k = 0; k < 64; ++k) acc = fmaf(sH2[k], sW3[k * 32 + tid], acc);
      acc = acc + sB3[tid];
      sDrift[tid] = acc;
      sA[tid] = pA;
      float K1 = (2.0f * pA) * sX[tid] + pBc;
      sK1[tid] = K1;
      sMb[tid] = xla_exp((-(K1 * K1)) / (4.0f * pA));
    }
    __syncthreads();

    // ---- Phase 2: tilt_w over (S,D) — 2 elems/thread
    {
      int d = tid & 31;
      float K1 = sK1[d], A = sA[d], dsv = sDs[d];
      float raw0, raw1;
      if (PRE) { raw0 = pRaw0; raw1 = pRaw1; }
      else {
        unsigned ks0 = sKeyStep[0], ks1 = sKeyStep[1];
        raw0 = 0.1f * powm(1.0f - u01(rbits(ks0, ks1, (unsigned)(b * 2048 + tid))));
        raw1 = 0.1f * powm(1.0f - u01(rbits(ks0, ks1, (unsigned)(b * 2048 + tid + 1024))));
      }
      float scaled = dsv * raw0;
      float quad = A * (scaled * scaled);
      float lin = K1 * scaled;
      float lh = 80.0f * xla_tanh((quad + lin) / 80.0f);
      float nh = 80.0f * xla_tanh((quad - lin) / 80.0f);
      sTilt[d * 65 + (tid >> 5)] = xla_exp(lh) + xla_exp(nh);
      scaled = dsv * raw1;
      quad = A * (scaled * scaled);
      lin = K1 * scaled;
      lh = 80.0f * xla_tanh((quad + lin) / 80.0f);
      nh = 80.0f * xla_tanh((quad - lin) / 80.0f);
      sTilt[d * 65 + ((tid + 1024) >> 5)] = xla_exp(lh) + xla_exp(nh);
    }
    __syncthreads();

    // ---- Phase 3a: per-d 95% quantile clip (wave bitonic sort, 2 d's/wave)
    {
      int wv = tid >> 6, lane = tid & 63;
      float vo0 = sTilt[wv * 65 + lane];
      float vo1 = sTilt[(wv + 16) * 65 + lane];
      float v0 = vo0, v1 = vo1;
      for (int k = 2; k <= 64; k <<= 1)
        for (int j = k >> 1; j > 0; j >>= 1) {
          float o0 = __shfl_xor(v0, j, 64);
          float o1 = __shfl_xor(v1, j, 64);
          bool keepmin = (((lane & j) == 0) == ((lane & k) == 0));
          v0 = keepmin ? fminf(v0, o0) : fmaxf(v0, o0);
          v1 = keepmin ? fminf(v1, o1) : fmaxf(v1, o1);
        }
      float qv = 0.95f * 63.0f;
      float hw = qv - 59.0f;
      float lw = 1.0f - hw;
      float s59 = __shfl(v0, 59, 64), s60 = __shfl(v0, 60, 64);
      float tq0 = s59 * lw + s60 * hw;
      s59 = __shfl(v1, 59, 64); s60 = __shfl(v1, 60, 64);
      float tq1 = s59 * lw + s60 * hw;
      sTilt[wv * 65 + lane] = fminf(vo0, tq0);
      sTilt[(wv + 16) * 65 + lane] = fminf(vo1, tq1);
    }
    __syncthreads();

    // ---- Phase 4: all 8 rejection attempts in parallel (4 tasks/thread)
    //      + Phase 3b (Poisson count) on threads 0..31
    {
#pragma unroll
      for (int q = 0; q < 4; ++q) {
        int tau = tid + q * 1024;
        int jd = tau >> 3, a = tau & 7, d = jd & 31;
        float A = sA[d], K1 = sK1[d];
        float K1sq = K1 * K1;
        float rp;
        if (PRE) rp = pRp[q];
        else rp = 0.1f * powm(1.0f - u01(rbits(sKpF[a * 2], sKpF[a * 2 + 1], (unsigned)(b * 512 + jd))));
        float rp2 = rp * rp;
        float den = fmaxf(1.0f - ((2.0f * A) * rp2) * SIG2F, 1e-6f);
        float Cv = xla_exp(((K1sq * rp2) * SIG2F) / (2.0f * den)) / sqrt_cr(den);
        float p = fminf(Cv / sMb[d], 1.0f);
        float u2 = u01(rbits(sKaF[a * 2], sKaF[a * 2 + 1], (unsigned)(b * 512 + jd)));
        sFlag[tau] = (u2 < p) ? (unsigned char)1 : (unsigned char)0;
        sRp[tau] = rp;
      }
      if (tid < 32) {
        float sum = 0.0f;
        for (int s = 0; s < 64; ++s) sum = sum + sTilt[tid * 65 + s];
        float tilt = sum / 64.0f;
        float lam = (tilt * RATE1F) * dt;
        float negl = -lam;
        int n = 0;
        if (PRE) {
#pragma unroll
          for (int k = 0; k < 17; ++k) n += (pLk[k] > negl) ? 1 : 0;
        } else {
          float L = 0.0f;
          for (int k = 0; k < 17; ++k) {
            float u = u01(rbits(sSubF[k * 2], sSubF[k * 2 + 1], (unsigned)(b * 32 + tid)));
            L = L + xla_log(u);
            n += (L > negl) ? 1 : 0;
          }
        }
        sNj[tid] = n;
      }
    }
    __syncthreads();

    // ---- Phase 5: select first accepted attempt, conditional gaussian
    if (tid < 512) {
      int jd = tid, d = jd & 31;
      float r = 0.1f;
      bool found = false;
#pragma unroll
      for (int a = 0; a < 8; ++a) {
        if (!found && sFlag[jd * 8 + a]) { r = sRp[jd * 8 + a]; found = true; }
      }
      float fz = u01(rbits(sKeyStep[6], sKeyStep[7], (unsigned)(b * 512 + jd)));
      float un = fmaxf(LO_N, fz * 2.0f + LO_N);
      float z = SQRT2F * xla_erfinv(un);
      float A = sA[d], K1 = sK1[d];
      float t2 = (2.0f * (r * r)) * SIG2F;
      float K2 = A - 1.0f / t2;
      float K2s = (K2 < -1e-6f) ? K2 : -1e-6f;
      float mean = (-K1) / (2.0f * K2s);
      float var = (-1.0f) / (2.0f * K2s);
      float cond = mean + sqrt_cr(var) * z;
      bool mk = (jd >> 5) < sNj[d];
      sCond[jd] = cond * (mk ? 1.0f : 0.0f);
    }
    __syncthreads();

    // ---- Phase 6: aggregate jumps, clip, update state, write output
    if (tid < 32) {
      int d = tid;
      float soj = 0.0f;
      for (int j = 0; j < 16; ++j) soj = soj + sCond[j * 32 + d];
      soj = 2.5f * xla_tanh(soj / 2.5f);
      float Xn = (sX[d] + sDrift[d] * dt) + sDs[d] * soj;
      sX[d] = Xn;
      out[ti * 1024 + b * 32 + d] = Xn;
    }
    __syncthreads();
    past_t = t;
  }
}

// ---------------------------------------------------------------- launch
extern "C" void kernel_launch(void* const* d_in, const int* in_sizes, int n_in,
                              void* d_out, int out_size, void* d_ws, size_t ws_size,
                              hipStream_t stream) {
  const float* state_init = (const float*)d_in[0];
  const float* tseq       = (const float*)d_in[1];
  const float* dW1        = (const float*)d_in[2];
  const float* db1        = (const float*)d_in[3];
  const float* dW2        = (const float*)d_in[4];
  const float* db2        = (const float*)d_in[5];
  const float* dW3        = (const float*)d_in[6];
  const float* db3        = (const float*)d_in[7];
  const float* diff_log   = (const float*)d_in[8];
  const float* pW1        = (const float*)d_in[9];
  const float* pb1        = (const float*)d_in[10];
  const float* pW2        = (const float*)d_in[11];
  const float* pb2        = (const float*)d_in[12];
  const float* pW3        = (const float*)d_in[13];
  const float* pb3        = (const float*)d_in[14];
  float* ws = (float*)d_ws;
  unsigned* wsu = (unsigned*)d_ws;

  bool pre = ws_size >= (size_t)WS_FLOATS_NEEDED * 4;

  key_kernel<<<1, 64, 0, stream>>>(wsu);
  phi_kernel<<<64, 64, 0, stream>>>(tseq, pW1, pb1, pW2, pb2, pW3, pb3, diff_log, ws);
  if (pre) {
    stable_kernel<<<4096, 256, 0, stream>>>(wsu, ws);
    lk_kernel<<<256, 256, 0, stream>>>(wsu, ws);
    sim_kernel<true><<<32, 1024, 0, stream>>>(state_init, tseq, dW1, db1, dW2, db2,
                                              dW3, db3, ws, wsu, (float*)d_out);
  } else {
    sim_kernel<false><<<32, 1024, 0, stream>>>(state_init, tseq, dW1, db1, dW2, db2,
                                               dW3, db3, ws, wsu, (float*)d_out);
  }
}

// Round 3
// 713.542 us; speedup vs baseline: 1.7644x; 1.4580x over previous
//
#include <hip/hip_runtime.h>
#include <cstdint>
#include <math.h>

// XLA CPU (no fast-math) emits unfused mul/add for all HLO-level elementwise ops.
#pragma clang fp contract(off)

#define DEV __device__ __forceinline__

// ---------------------------------------------------------------- threefry2x32
struct U2 { unsigned a, b; };

DEV unsigned rotl32(unsigned v, int d) { return (v << d) | (v >> (32 - d)); }

DEV U2 tf2(unsigned k0, unsigned k1, unsigned x0, unsigned x1) {
  unsigned ks2 = k0 ^ k1 ^ 0x1BD11BDAu;
  x0 += k0; x1 += k1;
#define TFR(r) { x0 += x1; x1 = rotl32(x1, r); x1 ^= x0; }
  TFR(13) TFR(15) TFR(26) TFR(6)
  x0 += k1; x1 += ks2 + 1u;
  TFR(17) TFR(29) TFR(16) TFR(24)
  x0 += ks2; x1 += k0 + 2u;
  TFR(13) TFR(15) TFR(26) TFR(6)
  x0 += k0; x1 += k1 + 3u;
  TFR(17) TFR(29) TFR(16) TFR(24)
  x0 += k1; x1 += ks2 + 4u;
  TFR(13) TFR(15) TFR(26) TFR(6)
  x0 += ks2; x1 += k0 + 5u;
#undef TFR
  U2 r; r.a = x0; r.b = x1; return r;
}

DEV unsigned rbits(unsigned k0, unsigned k1, unsigned idx) {
  U2 o = tf2(k0, k1, 0u, idx);
  return o.a ^ o.b;
}

DEV float u01(unsigned bits) {
  return __uint_as_float((bits >> 9) | 0x3F800000u) - 1.0f;
}

// ---------------------------------------------------------------- XLA CPU math
DEV float xla_exp(float xi) {
  float x = fminf(fmaxf(xi, -88.3762626647949f), 88.3762626647950f);
  float fx = floorf(x * 1.44269504088896341f + 0.5f);
  float tmp = 0.693359375f * fx;
  float z = -2.12194440e-4f * fx;
  x = x - tmp;
  x = x - z;
  z = x * x;
  float y = 1.9875691500e-4f * x + 1.3981999507e-3f;
  y = y * x + 8.3334519073e-3f;
  y = y * x + 4.1665795894e-2f;
  y = y * x + 1.6666665459e-1f;
  y = y * x + 5.0000001201e-1f;
  y = y * z + x;
  y = y + 1.0f;
  int n = (int)fx;
  float two_n = __uint_as_float((unsigned)(n + 127) << 23);
  return fmaxf(y * two_n, xi);
}

DEV float xla_log(float xi) {
  float xc = fmaxf(xi, 1.17549435082228751e-38f);
  unsigned bits = __float_as_uint(xc);
  float e = (float)((int)(bits >> 23) - 126);
  float m = __uint_as_float((bits & 0x007FFFFFu) | 0x3F000000u);
  bool msk = m < 0.707106781186547524f;
  float tmp = msk ? m : 0.0f;
  float em  = msk ? 1.0f : 0.0f;
  m = m - 1.0f;
  e = e - em;
  m = m + tmp;
  float z  = m * m;
  float x3 = z * m;
  float y0 = 7.0376836292e-2f  * m + -1.1514610310e-1f;
  float y1 = -1.2420140846e-1f * m + 1.4249322787e-1f;
  float y2 = 2.0000714765e-1f  * m + -2.4999993993e-1f;
  y0 = y0 * m + 1.1676998740e-1f;
  y1 = y1 * m + -1.6668057665e-1f;
  y2 = y2 * m + 3.3333331174e-1f;
  y0 = y0 * x3 + y1;
  y0 = y0 * x3 + y2;
  y0 = y0 * x3;
  y0 = -2.12194440e-4f * e + y0;
  y0 = y0 - 0.5f * z;
  float r = m + y0;
  r = 0.693359375f * e + r;
  if (!(xi > 0.0f)) r = (xi == 0.0f) ? -__builtin_inff() : __builtin_nanf("");
  if (xi == __builtin_inff()) r = __builtin_inff();
  return r;
}

DEV float xla_tanh(float x) {
  float xc = fminf(fmaxf(x, -9.0f), 9.0f);
  float x2 = xc * xc;
  float p = x2 * -2.76076847742355e-16f + 2.00018790482477e-13f;
  p = p * x2 + -8.60467152213735e-11f;
  p = p * x2 + 5.12229709037114e-08f;
  p = p * x2 + 1.48572235717979e-05f;
  p = p * x2 + 6.37261928875436e-04f;
  p = p * x2 + 4.89352455891786e-03f;
  p = xc * p;
  float q = x2 * 1.19825839466702e-06f + 1.18534705686654e-04f;
  q = q * x2 + 2.26843463243900e-03f;
  q = q * x2 + 4.89352518554385e-03f;
  float r = p / q;
  return (fabsf(x) < 0.0004f) ? x : r;
}

DEV float sqrt_cr(float x) { return (float)sqrt((double)x); }

DEV float xla_log1p(float x) {
  float fl = xla_log(x + 1.0f);
  float fs = ((-0.5f) * x + 1.0f) * x;
  return (fabsf(x) < 1e-4f) ? fs : fl;
}

DEV float softplus_ref(float x) {
  float amax = fmaxf(x, 0.0f);
  return amax + xla_log1p(xla_exp(-fabsf(x)));
}

DEV float xla_erfinv(float x) {
  float w = -xla_log1p(-(x * x));
  bool lt = w < 5.0f;
  float wa = lt ? (w - 2.5f) : (sqrt_cr(w) - 3.0f);
  float p;
  if (lt) {
    p = 2.81022636e-08f;
    p = p * wa + 3.43273939e-07f;
    p = p * wa + -3.5233877e-06f;
    p = p * wa + -4.39150654e-06f;
    p = p * wa + 0.00021858087f;
    p = p * wa + -0.00125372503f;
    p = p * wa + -0.00417768164f;
    p = p * wa + 0.246640727f;
    p = p * wa + 1.50140941f;
  } else {
    p = -0.000200214257f;
    p = p * wa + 0.000100950558f;
    p = p * wa + 0.00134934322f;
    p = p * wa + -0.00367342844f;
    p = p * wa + 0.00573950773f;
    p = p * wa + -0.0076224613f;
    p = p * wa + 0.00943887047f;
    p = p * wa + 1.00167406f;
    p = p * wa + 2.83297682f;
  }
  return p * x;
}

DEV float powm(float x) {
  const double e = (double)((float)(-1.0 / 1.2));
  return (float)pow((double)x, e);
}

// ---------------------------------------------------------------- constants
#define Bn 32
#define Tn 64
#define Dn 32
#define Sn 64
#define Jn 16
#define SIG2F  0.0025000000000000005f
#define RATE1F 13.207443270509278f
#define LO_N  -0.99999994039535522f
#define SQRT2F 1.4142135623730951f

// ws layout (float / uint indices)
#define OFF_A    0          // 2048
#define OFF_B    2048       // 2048
#define OFF_DS   4096       // 32
#define OFF_KEYS 4128       // 64*8 uints
#define OFF_KA   4640       // 64*8*2 uints
#define OFF_KP   5664       // 64*8*2 uints
#define OFF_SUB  6688       // 64*17*2 uints
#define OFF_RAW  16384      // 4194304 floats
#define OFF_RP   4210688    // 8388608 floats
#define OFF_LK   12599296   // 1114112 floats  (end 13713408 = MODE1 boundary)
#define OFF_U2   13713408   // 8388608 floats
#define OFF_Z    22102016   // 1048576 floats  (end 23150592 = MODE2 boundary)
#define WS_FLOATS_M1 13713408
#define WS_FLOATS_M2 23150592
#define NRAW 4194304
#define NRP  8388608
#define NU2  8388608
#define NZ   1048576
#define NLK  65536

// ---------------------------------------------------------------- key tables
__global__ void __launch_bounds__(64) key_kernel(unsigned* __restrict__ wsu) {
  __shared__ unsigned lk[64][2];
  int t = threadIdx.x;
  if (t == 0) {
    unsigned k0 = 0u, k1 = 42u;   // jax.random.key(42)
    for (int i = 0; i < 64; ++i) {
      lk[i][0] = k0; lk[i][1] = k1;
      U2 c0 = tf2(k0, k1, 0u, 0u);
      k0 = c0.a; k1 = c0.b;
    }
  }
  __syncthreads();
  unsigned k0 = lk[t][0], k1 = lk[t][1];
  U2 c1 = tf2(k0, k1, 0u, 1u);  // k_stab
  U2 c2 = tf2(k0, k1, 0u, 2u);  // k_pois
  U2 c3 = tf2(k0, k1, 0u, 3u);  // k_rej
  U2 c4 = tf2(k0, k1, 0u, 4u);  // k_gauss
  wsu[OFF_KEYS + t * 8 + 0] = c1.a; wsu[OFF_KEYS + t * 8 + 1] = c1.b;
  wsu[OFF_KEYS + t * 8 + 2] = c2.a; wsu[OFF_KEYS + t * 8 + 3] = c2.b;
  wsu[OFF_KEYS + t * 8 + 4] = c3.a; wsu[OFF_KEYS + t * 8 + 5] = c3.b;
  wsu[OFF_KEYS + t * 8 + 6] = c4.a; wsu[OFF_KEYS + t * 8 + 7] = c4.b;
  unsigned a0 = c3.a, a1 = c3.b;
  for (int a = 0; a < 8; ++a) {
    U2 kp = tf2(a0, a1, 0u, 1u);
    U2 ka = tf2(a0, a1, 0u, 2u);
    U2 nx = tf2(a0, a1, 0u, 0u);
    wsu[OFF_KP + (t * 8 + a) * 2 + 0] = kp.a; wsu[OFF_KP + (t * 8 + a) * 2 + 1] = kp.b;
    wsu[OFF_KA + (t * 8 + a) * 2 + 0] = ka.a; wsu[OFF_KA + (t * 8 + a) * 2 + 1] = ka.b;
    a0 = nx.a; a1 = nx.b;
  }
  unsigned r0 = c2.a, r1 = c2.b;
  for (int k = 0; k < 17; ++k) {
    U2 sub = tf2(r0, r1, 0u, 1u);
    U2 nx  = tf2(r0, r1, 0u, 0u);
    wsu[OFF_SUB + (t * 17 + k) * 2 + 0] = sub.a; wsu[OFF_SUB + (t * 17 + k) * 2 + 1] = sub.b;
    r0 = nx.a; r1 = nx.b;
  }
}

// ---------------------------------------------------------------- precompute (raw, rp [, u2, z, lk])
template <bool FULL>
__global__ void __launch_bounds__(256) stable_kernel(const unsigned* __restrict__ wsu,
                                                     float* __restrict__ ws) {
  const int NTOT = FULL ? (NRAW + NRP + NU2 + NZ + NLK) : (NRAW + NRP);
  int stride = gridDim.x * blockDim.x;
  for (int idx = blockIdx.x * blockDim.x + threadIdx.x; idx < NTOT; idx += stride) {
    if (idx < NRAW) {
      int t = idx >> 16;
      int b = (idx >> 11) & 31;
      int e = idx & 2047;
      unsigned k0 = wsu[OFF_KEYS + t * 8 + 0], k1 = wsu[OFF_KEYS + t * 8 + 1];
      float u = u01(rbits(k0, k1, (unsigned)(b * 2048 + e)));
      ws[OFF_RAW + idx] = 0.1f * powm(1.0f - u);
    } else if (idx < NRAW + NRP) {
      int i2 = idx - NRAW;
      int t = i2 >> 17;
      int b = (i2 >> 12) & 31;
      int jd = (i2 >> 3) & 511;
      int a = i2 & 7;
      unsigned k0 = wsu[OFF_KP + (t * 8 + a) * 2], k1 = wsu[OFF_KP + (t * 8 + a) * 2 + 1];
      float u1 = u01(rbits(k0, k1, (unsigned)(b * 512 + jd)));
      ws[OFF_RP + i2] = 0.1f * powm(1.0f - u1);
    } else if (FULL && idx < NRAW + NRP + NU2) {
      int i3 = idx - (NRAW + NRP);
      int t = i3 >> 17;
      int b = (i3 >> 12) & 31;
      int jd = (i3 >> 3) & 511;
      int a = i3 & 7;
      unsigned k0 = wsu[OFF_KA + (t * 8 + a) * 2], k1 = wsu[OFF_KA + (t * 8 + a) * 2 + 1];
      ws[OFF_U2 + i3] = u01(rbits(k0, k1, (unsigned)(b * 512 + jd)));
    } else if (FULL && idx < NRAW + NRP + NU2 + NZ) {
      int i4 = idx - (NRAW + NRP + NU2);
      int t = i4 >> 14;
      int b = (i4 >> 9) & 31;
      int jd = i4 & 511;
      unsigned k0 = wsu[OFF_KEYS + t * 8 + 6], k1 = wsu[OFF_KEYS + t * 8 + 7];
      float fz = u01(rbits(k0, k1, (unsigned)(b * 512 + jd)));
      float un = fmaxf(LO_N, fz * 2.0f + LO_N);
      ws[OFF_Z + i4] = SQRT2F * xla_erfinv(un);
    } else if (FULL) {
      int i5 = idx - (NRAW + NRP + NU2 + NZ);
      int t = i5 >> 10;
      int b = (i5 >> 5) & 31;
      int d = i5 & 31;
      float L = 0.0f;
      for (int k = 0; k < 17; ++k) {
        unsigned s0 = wsu[OFF_SUB + (t * 17 + k) * 2], s1 = wsu[OFF_SUB + (t * 17 + k) * 2 + 1];
        float u = u01(rbits(s0, s1, (unsigned)(b * 32 + d)));
        L = L + xla_log(u);
        ws[OFF_LK + ((t * 32 + b) * 17 + k) * 32 + d] = L;
      }
    }
  }
}

// LK for MODE1 (kept from R2)
__global__ void __launch_bounds__(256) lk_kernel(const unsigned* __restrict__ wsu,
                                                 float* __restrict__ ws) {
  int idx = blockIdx.x * 256 + threadIdx.x;
  int t = idx >> 10;
  int b = (idx >> 5) & 31;
  int d = idx & 31;
  float L = 0.0f;
  for (int k = 0; k < 17; ++k) {
    unsigned s0 = wsu[OFF_SUB + (t * 17 + k) * 2], s1 = wsu[OFF_SUB + (t * 17 + k) * 2 + 1];
    float u = u01(rbits(s0, s1, (unsigned)(b * 32 + d)));
    L = L + xla_log(u);
    ws[OFF_LK + ((t * 32 + b) * 17 + k) * 32 + d] = L;
  }
}

// ---------------------------------------------------------------- phi precompute
__global__ void __launch_bounds__(64) phi_kernel(
    const float* __restrict__ tseq,
    const float* __restrict__ pW1, const float* __restrict__ pb1,
    const float* __restrict__ pW2, const float* __restrict__ pb2,
    const float* __restrict__ pW3, const float* __restrict__ pb3,
    const float* __restrict__ diff_log, float* __restrict__ ws) {
  __shared__ float h1[64], h2[64];
  int t = blockIdx.x, w = threadIdx.x;
  float tv = tseq[t];
  h1[w] = xla_tanh(tv * pW1[w] + pb1[w]);
  __syncthreads();
  float acc = 0.0f;
  for (int k = 0; k < 64; ++k) acc = fmaf(h1[k], pW2[k * 64 + w], acc);
  acc = acc + pb2[w];
  h2[w] = xla_tanh(acc);
  __syncthreads();
  acc = 0.0f;
  for (int k = 0; k < 64; ++k) acc = fmaf(h2[k], pW3[k * 64 + w], acc);
  acc = acc + pb3[w];
  if (w < 32) ws[OFF_A + t * 32 + w] = -softplus_ref(acc);
  else        ws[OFF_B + t * 32 + (w - 32)] = acc;
  if (t == 0 && w < 32) ws[OFF_DS + w] = softplus_ref(diff_log[w]);
}

// ---------------------------------------------------------------- MODE2 sim: 5 barriers/step
__global__ void __launch_bounds__(1024) sim2_kernel(
    const float* __restrict__ state_init, const float* __restrict__ tseq,
    const float* __restrict__ gW1, const float* __restrict__ gb1,
    const float* __restrict__ gW2, const float* __restrict__ gb2,
    const float* __restrict__ gW3, const float* __restrict__ gb3,
    const float* __restrict__ ws, float* __restrict__ out) {
  const int b = blockIdx.x;
  const int tid = threadIdx.x;

  __shared__ float sW1[33 * 64], sB1[64], sW2[64 * 64], sB2[64], sW3[64 * 32], sB3[32];
  __shared__ float sTseq[64];
  __shared__ float sX[32], sK1[32], sA[32], sMb[32], sDrift[32], sDs[32];
  __shared__ int   sNj[32];
  __shared__ float sH1[64], sH2[64];
  __shared__ float sTilt[32 * 65];
  __shared__ float sRp[4096];      // sign bit = accept flag
  __shared__ float sCond[512];

  for (int i = tid; i < 33 * 64; i += 1024) sW1[i] = gW1[i];
  for (int i = tid; i < 64 * 64; i += 1024) sW2[i] = gW2[i];
  for (int i = tid; i < 64 * 32; i += 1024) sW3[i] = gW3[i];
  if (tid < 64) { sB1[tid] = gb1[tid]; sB2[tid] = gb2[tid]; sTseq[tid] = tseq[tid]; }
  if (tid < 32) { sB3[tid] = gb3[tid]; sX[tid] = state_init[b * 32 + tid]; sDs[tid] = ws[OFF_DS + tid]; }
  __syncthreads();

  // preamble: K1/Mb for step 0
  if (tid < 32) {
    float A = ws[OFF_A + tid], Bv = ws[OFF_B + tid];
    sA[tid] = A;
    float K1 = (2.0f * A) * sX[tid] + Bv;
    sK1[tid] = K1;
    sMb[tid] = xla_exp((-(K1 * K1)) / (4.0f * A));
  }

  // prefetch step 0
  int zi = tid & 511;
  float cRaw0, cRaw1, cRaw2, cRp[4], cU2[4], cZ;
  {
    int rawb = OFF_RAW + b * 2048;
    cRaw0 = ws[rawb + tid];                       // tid>=960 unused (valid addr)
    cRaw1 = (tid < 960) ? ws[rawb + 960 + tid] : 0.0f;
    cRaw2 = (tid < 128) ? ws[rawb + 1920 + tid] : 0.0f;
    int cb = b * 4096;
#pragma unroll
    for (int q = 0; q < 4; ++q) {
      cRp[q] = ws[OFF_RP + cb + tid + q * 1024];
      cU2[q] = ws[OFF_U2 + cb + tid + q * 1024];
    }
    cZ = ws[OFF_Z + b * 512 + zi];
  }
  __syncthreads();

  float past_t = sTseq[0];

  for (int ti = 0; ti < Tn; ++ti) {
    float t = sTseq[ti];
    float dt = t - past_t;

    // ---- issue next-step prefetch (drains at end-of-P1 barrier)
    int tn = (ti < 63) ? ti + 1 : 63;
    float nRaw0, nRaw1, nRaw2, nRp[4], nU2[4], nZ, nA = 0.0f, nB = 0.0f;
    {
      int rawb = OFF_RAW + (tn * 32 + b) * 2048;
      nRaw0 = ws[rawb + tid];
      nRaw1 = (tid < 960) ? ws[rawb + 960 + tid] : 0.0f;
      nRaw2 = (tid < 128) ? ws[rawb + 1920 + tid] : 0.0f;
      int cb = (tn * 32 + b) * 4096;
#pragma unroll
      for (int q = 0; q < 4; ++q) {
        nRp[q] = ws[OFF_RP + cb + tid + q * 1024];
        nU2[q] = ws[OFF_U2 + cb + tid + q * 1024];
      }
      nZ = ws[OFF_Z + (tn * 32 + b) * 512 + zi];
      if (tid < 32) { nA = ws[OFF_A + tn * 32 + tid]; nB = ws[OFF_B + tn * 32 + tid]; }
    }

    // ---- P1: waves 0-14 tilt; wave 15 full drift MLP (same-wave LDS, no barrier)
    if (tid >= 960) {
      int l = tid - 960;
      float acc = 0.0f;
      acc = fmaf(t, sW1[l], acc);
      for (int k = 1; k < 33; ++k) acc = fmaf(sX[k - 1], sW1[k * 64 + l], acc);
      acc = acc + sB1[l];
      sH1[l] = xla_tanh(acc);
      float acc2 = 0.0f;
      for (int k = 0; k < 64; ++k) acc2 = fmaf(sH1[k], sW2[k * 64 + l], acc2);
      acc2 = acc2 + sB2[l];
      sH2[l] = xla_tanh(acc2);
      if (l < 32) {
        float a3 = 0.0f;
        for (int k = 0; k < 64; ++k) a3 = fmaf(sH2[k], sW3[k * 32 + l], a3);
        a3 = a3 + sB3[l];
        sDrift[l] = a3;
      }
    } else {
      int d0 = tid & 31;
      float K1 = sK1[d0], A = sA[d0], dsv = sDs[d0];
      // task e = tid
      {
        float scaled = dsv * cRaw0;
        float quad = A * (scaled * scaled);
        float lin = K1 * scaled;
        float lh = 80.0f * xla_tanh((quad + lin) / 80.0f);
        float nh = 80.0f * xla_tanh((quad - lin) / 80.0f);
        sTilt[d0 * 65 + (tid >> 5)] = xla_exp(lh) + xla_exp(nh);
      }
      // task e = tid + 960
      {
        int e = tid + 960, d = e & 31;
        float K1b = sK1[d], Ab = sA[d], dsb = sDs[d];
        float scaled = dsb * cRaw1;
        float quad = Ab * (scaled * scaled);
        float lin = K1b * scaled;
        float lh = 80.0f * xla_tanh((quad + lin) / 80.0f);
        float nh = 80.0f * xla_tanh((quad - lin) / 80.0f);
        sTilt[d * 65 + (e >> 5)] = xla_exp(lh) + xla_exp(nh);
      }
      // task e = 1920 + tid (tid < 128)
      if (tid < 128) {
        int e = 1920 + tid, d = e & 31;
        float K1b = sK1[d], Ab = sA[d], dsb = sDs[d];
        float scaled = dsb * cRaw2;
        float quad = Ab * (scaled * scaled);
        float lin = K1b * scaled;
        float lh = 80.0f * xla_tanh((quad + lin) / 80.0f);
        float nh = 80.0f * xla_tanh((quad - lin) / 80.0f);
        sTilt[d * 65 + (e >> 5)] = xla_exp(lh) + xla_exp(nh);
      }
    }
    __syncthreads();

    // ---- P2: per-d 95% quantile clip (wave bitonic sort, 2 d's/wave)
    {
      int wv = tid >> 6, lane = tid & 63;
      float vo0 = sTilt[wv * 65 + lane];
      float vo1 = sTilt[(wv + 16) * 65 + lane];
      float v0 = vo0, v1 = vo1;
      for (int k = 2; k <= 64; k <<= 1)
        for (int j = k >> 1; j > 0; j >>= 1) {
          float o0 = __shfl_xor(v0, j, 64);
          float o1 = __shfl_xor(v1, j, 64);
          bool keepmin = (((lane & j) == 0) == ((lane & k) == 0));
          v0 = keepmin ? fminf(v0, o0) : fmaxf(v0, o0);
          v1 = keepmin ? fminf(v1, o1) : fmaxf(v1, o1);
        }
      float qv = 0.95f * 63.0f;
      float hw = qv - 59.0f;
      float lw = 1.0f - hw;
      float s59 = __shfl(v0, 59, 64), s60 = __shfl(v0, 60, 64);
      float tq0 = s59 * lw + s60 * hw;
      s59 = __shfl(v1, 59, 64); s60 = __shfl(v1, 60, 64);
      float tq1 = s59 * lw + s60 * hw;
      sTilt[wv * 65 + lane] = fminf(vo0, tq0);
      sTilt[(wv + 16) * 65 + lane] = fminf(vo1, tq1);
    }
    __syncthreads();

    // ---- P3: 8 rejection attempts (4 cand/thread) + Poisson on threads 0-31
    {
#pragma unroll
      for (int q = 0; q < 4; ++q) {
        int tau = tid + q * 1024;
        int d = (tau >> 3) & 31;
        float A = sA[d], K1 = sK1[d];
        float K1sq = K1 * K1;
        float rp = cRp[q];
        float rp2 = rp * rp;
        float den = fmaxf(1.0f - ((2.0f * A) * rp2) * SIG2F, 1e-6f);
        float Cv = xla_exp(((K1sq * rp2) * SIG2F) / (2.0f * den)) / sqrt_cr(den);
        float p = fminf(Cv / sMb[d], 1.0f);
        sRp[tau] = (cU2[q] < p) ? rp : -rp;
      }
      if (tid < 32) {
        float lk[17];
#pragma unroll
        for (int k = 0; k < 17; ++k) lk[k] = ws[OFF_LK + ((ti * 32 + b) * 17 + k) * 32 + tid];
        float sum = 0.0f;
        for (int s = 0; s < 64; ++s) sum = sum + sTilt[tid * 65 + s];
        float tilt = sum / 64.0f;
        float lam = (tilt * RATE1F) * dt;
        float negl = -lam;
        int n = 0;
#pragma unroll
        for (int k = 0; k < 17; ++k) n += (lk[k] > negl) ? 1 : 0;
        sNj[tid] = n;
      }
    }
    __syncthreads();

    // ---- P4: select first accepted attempt + conditional gaussian (tid<512)
    if (tid < 512) {
      int jd = tid, d = jd & 31;
      float r = 0.1f;
      bool found = false;
#pragma unroll
      for (int a = 0; a < 8; ++a) {
        float v = sRp[jd * 8 + a];
        if (!found && v > 0.0f) { r = v; found = true; }
      }
      float z = cZ;
      float A = sA[d], K1 = sK1[d];
      float t2 = (2.0f * (r * r)) * SIG2F;
      float K2 = A - 1.0f / t2;
      float K2s = (K2 < -1e-6f) ? K2 : -1e-6f;
      float mean = (-K1) / (2.0f * K2s);
      float var = (-1.0f) / (2.0f * K2s);
      float cond = mean + sqrt_cr(var) * z;
      bool mk = (jd >> 5) < sNj[d];
      sCond[jd] = cond * (mk ? 1.0f : 0.0f);
    }
    __syncthreads();

    // ---- P5: aggregate jumps, update state, write out, next-step K1/Mb
    if (tid < 32) {
      int d = tid;
      float soj = 0.0f;
      for (int j = 0; j < 16; ++j) soj = soj + sCond[j * 32 + d];
      soj = 2.5f * xla_tanh(soj / 2.5f);
      float Xn = (sX[d] + sDrift[d] * dt) + sDs[d] * soj;
      sX[d] = Xn;
      out[ti * 1024 + b * 32 + d] = Xn;
      sA[d] = nA;
      float K1n = (2.0f * nA) * Xn + nB;
      sK1[d] = K1n;
      sMb[d] = xla_exp((-(K1n * K1n)) / (4.0f * nA));
    }
    __syncthreads();

    // rotate prefetch regs
    cRaw0 = nRaw0; cRaw1 = nRaw1; cRaw2 = nRaw2;
#pragma unroll
    for (int q = 0; q < 4; ++q) { cRp[q] = nRp[q]; cU2[q] = nU2[q]; }
    cZ = nZ;
    past_t = t;
  }
}

// ---------------------------------------------------------------- MODE1/0 sim (R2, proven)
template <bool PRE>
__global__ void __launch_bounds__(1024) sim_kernel(
    const float* __restrict__ state_init, const float* __restrict__ tseq,
    const float* __restrict__ gW1, const float* __restrict__ gb1,
    const float* __restrict__ gW2, const float* __restrict__ gb2,
    const float* __restrict__ gW3, const float* __restrict__ gb3,
    const float* __restrict__ ws, const unsigned* __restrict__ wsu,
    float* __restrict__ out) {
  const int b = blockIdx.x;
  const int tid = threadIdx.x;

  __shared__ float sW1[33 * 64], sB1[64], sW2[64 * 64], sB2[64], sW3[64 * 32], sB3[32];
  __shared__ float sTseq[64];
  __shared__ float sX[32], sK1[32], sA[32], sMb[32], sDrift[32], sDs[32];
  __shared__ int   sNj[32];
  __shared__ float sH1[64], sH2[64];
  __shared__ float sTilt[32 * 65];
  __shared__ float sCond[512];
  __shared__ float sRp[4096];
  __shared__ unsigned char sFlag[4096];
  __shared__ unsigned sKeyStep[8], sKaF[16], sKpF[16], sSubF[34];

  for (int i = tid; i < 33 * 64; i += 1024) sW1[i] = gW1[i];
  for (int i = tid; i < 64 * 64; i += 1024) sW2[i] = gW2[i];
  for (int i = tid; i < 64 * 32; i += 1024) sW3[i] = gW3[i];
  if (tid < 64) { sB1[tid] = gb1[tid]; sB2[tid] = gb2[tid]; sTseq[tid] = tseq[tid]; }
  if (tid < 32) { sB3[tid] = gb3[tid]; sX[tid] = state_init[b * 32 + tid]; sDs[tid] = ws[OFF_DS + tid]; }
  __syncthreads();

  float past_t = sTseq[0];

  for (int ti = 0; ti < Tn; ++ti) {
    float t = sTseq[ti];
    float dt = t - past_t;

    float pRaw0 = 0.0f, pRaw1 = 0.0f, pRp[4] = {0, 0, 0, 0};
    float pLk[17];
    float pA = 0.0f, pBc = 0.0f;
    if (PRE) {
      int rawbase = (ti * 32 + b) * 2048;
      pRaw0 = ws[OFF_RAW + rawbase + tid];
      pRaw1 = ws[OFF_RAW + rawbase + tid + 1024];
      int rpbase = (ti * 32 + b) * 4096;
#pragma unroll
      for (int q = 0; q < 4; ++q) pRp[q] = ws[OFF_RP + rpbase + tid + q * 1024];
    }
    if (tid < 32) {
      if (PRE) {
#pragma unroll
        for (int k = 0; k < 17; ++k) pLk[k] = ws[OFF_LK + ((ti * 32 + b) * 17 + k) * 32 + tid];
      }
      pA  = ws[OFF_A + ti * 32 + tid];
      pBc = ws[OFF_B + ti * 32 + tid];
    }
    if (tid < 8)  sKeyStep[tid] = wsu[OFF_KEYS + ti * 8 + tid];
    if (tid >= 8  && tid < 24) sKaF[tid - 8]  = wsu[OFF_KA + ti * 16 + (tid - 8)];
    if (tid >= 24 && tid < 40) sKpF[tid - 24] = wsu[OFF_KP + ti * 16 + (tid - 24)];
    if (tid >= 40 && tid < 74) sSubF[tid - 40] = wsu[OFF_SUB + ti * 34 + (tid - 40)];

    if (tid < 64) {
      float acc = 0.0f;
      acc = fmaf(t, sW1[tid], acc);
      for (int k = 1; k < 33; ++k) acc = fmaf(sX[k - 1], sW1[k * 64 + tid], acc);
      acc = acc + sB1[tid];
      sH1[tid] = xla_tanh(acc);
    }
    __syncthreads();
    if (tid < 64) {
      float acc = 0.0f;
      for (int k = 0; k < 64; ++k) acc = fmaf(sH1[k], sW2[k * 64 + tid], acc);
      acc = acc + sB2[tid];
      sH2[tid] = xla_tanh(acc);
    }
    __syncthreads();
    if (tid < 32) {
      float acc = 0.0f;
      for (int k = 0; k < 64; ++k) acc = fmaf(sH2[k], sW3[k * 32 + tid], acc);
      acc = acc + sB3[tid];
      sDrift[tid] = acc;
      sA[tid] = pA;
      float K1 = (2.0f * pA) * sX[tid] + pBc;
      sK1[tid] = K1;
      sMb[tid] = xla_exp((-(K1 * K1)) / (4.0f * pA));
    }
    __syncthreads();

    {
      int d = tid & 31;
      float K1 = sK1[d], A = sA[d], dsv = sDs[d];
      float raw0, raw1;
      if (PRE) { raw0 = pRaw0; raw1 = pRaw1; }
      else {
        unsigned ks0 = sKeyStep[0], ks1 = sKeyStep[1];
        raw0 = 0.1f * powm(1.0f - u01(rbits(ks0, ks1, (unsigned)(b * 2048 + tid))));
        raw1 = 0.1f * powm(1.0f - u01(rbits(ks0, ks1, (unsigned)(b * 2048 + tid + 1024))));
      }
      float scaled = dsv * raw0;
      float quad = A * (scaled * scaled);
      float lin = K1 * scaled;
      float lh = 80.0f * xla_tanh((quad + lin) / 80.0f);
      float nh = 80.0f * xla_tanh((quad - lin) / 80.0f);
      sTilt[d * 65 + (tid >> 5)] = xla_exp(lh) + xla_exp(nh);
      scaled = dsv * raw1;
      quad = A * (scaled * scaled);
      lin = K1 * scaled;
      lh = 80.0f * xla_tanh((quad + lin) / 80.0f);
      nh = 80.0f * xla_tanh((quad - lin) / 80.0f);
      sTilt[d * 65 + ((tid + 1024) >> 5)] = xla_exp(lh) + xla_exp(nh);
    }
    __syncthreads();

    {
      int wv = tid >> 6, lane = tid & 63;
      float vo0 = sTilt[wv * 65 + lane];
      float vo1 = sTilt[(wv + 16) * 65 + lane];
      float v0 = vo0, v1 = vo1;
      for (int k = 2; k <= 64; k <<= 1)
        for (int j = k >> 1; j > 0; j >>= 1) {
          float o0 = __shfl_xor(v0, j, 64);
          float o1 = __shfl_xor(v1, j, 64);
          bool keepmin = (((lane & j) == 0) == ((lane & k) == 0));
          v0 = keepmin ? fminf(v0, o0) : fmaxf(v0, o0);
          v1 = keepmin ? fminf(v1, o1) : fmaxf(v1, o1);
        }
      float qv = 0.95f * 63.0f;
      float hw = qv - 59.0f;
      float lw = 1.0f - hw;
      float s59 = __shfl(v0, 59, 64), s60 = __shfl(v0, 60, 64);
      float tq0 = s59 * lw + s60 * hw;
      s59 = __shfl(v1, 59, 64); s60 = __shfl(v1, 60, 64);
      float tq1 = s59 * lw + s60 * hw;
      sTilt[wv * 65 + lane] = fminf(vo0, tq0);
      sTilt[(wv + 16) * 65 + lane] = fminf(vo1, tq1);
    }
    __syncthreads();

    {
#pragma unroll
      for (int q = 0; q < 4; ++q) {
        int tau = tid + q * 1024;
        int jd = tau >> 3, a = tau & 7, d = jd & 31;
        float A = sA[d], K1 = sK1[d];
        float K1sq = K1 * K1;
        float rp;
        if (PRE) rp = pRp[q];
        else rp = 0.1f * powm(1.0f - u01(rbits(sKpF[a * 2], sKpF[a * 2 + 1], (unsigned)(b * 512 + jd))));
        float rp2 = rp * rp;
        float den = fmaxf(1.0f - ((2.0f * A) * rp2) * SIG2F, 1e-6f);
        float Cv = xla_exp(((K1sq * rp2) * SIG2F) / (2.0f * den)) / sqrt_cr(den);
        float p = fminf(Cv / sMb[d], 1.0f);
        float u2 = u01(rbits(sKaF[a * 2], sKaF[a * 2 + 1], (unsigned)(b * 512 + jd)));
        sFlag[tau] = (u2 < p) ? (unsigned char)1 : (unsigned char)0;
        sRp[tau] = rp;
      }
      if (tid < 32) {
        float sum = 0.0f;
        for (int s = 0; s < 64; ++s) sum = sum + sTilt[tid * 65 + s];
        float tilt = sum / 64.0f;
        float lam = (tilt * RATE1F) * dt;
        float negl = -lam;
        int n = 0;
        if (PRE) {
#pragma unroll
          for (int k = 0; k < 17; ++k) n += (pLk[k] > negl) ? 1 : 0;
        } else {
          float L = 0.0f;
          for (int k = 0; k < 17; ++k) {
            float u = u01(rbits(sSubF[k * 2], sSubF[k * 2 + 1], (unsigned)(b * 32 + tid)));
            L = L + xla_log(u);
            n += (L > negl) ? 1 : 0;
          }
        }
        sNj[tid] = n;
      }
    }
    __syncthreads();

    if (tid < 512) {
      int jd = tid, d = jd & 31;
      float r = 0.1f;
      bool found = false;
#pragma unroll
      for (int a = 0; a < 8; ++a) {
        if (!found && sFlag[jd * 8 + a]) { r = sRp[jd * 8 + a]; found = true; }
      }
      float fz = u01(rbits(sKeyStep[6], sKeyStep[7], (unsigned)(b * 512 + jd)));
      float un = fmaxf(LO_N, fz * 2.0f + LO_N);
      float z = SQRT2F * xla_erfinv(un);
      float A = sA[d], K1 = sK1[d];
      float t2 = (2.0f * (r * r)) * SIG2F;
      float K2 = A - 1.0f / t2;
      float K2s = (K2 < -1e-6f) ? K2 : -1e-6f;
      float mean = (-K1) / (2.0f * K2s);
      float var = (-1.0f) / (2.0f * K2s);
      float cond = mean + sqrt_cr(var) * z;
      bool mk = (jd >> 5) < sNj[d];
      sCond[jd] = cond * (mk ? 1.0f : 0.0f);
    }
    __syncthreads();

    if (tid < 32) {
      int d = tid;
      float soj = 0.0f;
      for (int j = 0; j < 16; ++j) soj = soj + sCond[j * 32 + d];
      soj = 2.5f * xla_tanh(soj / 2.5f);
      float Xn = (sX[d] + sDrift[d] * dt) + sDs[d] * soj;
      sX[d] = Xn;
      out[ti * 1024 + b * 32 + d] = Xn;
    }
    __syncthreads();
    past_t = t;
  }
}

// ---------------------------------------------------------------- launch
extern "C" void kernel_launch(void* const* d_in, const int* in_sizes, int n_in,
                              void* d_out, int out_size, void* d_ws, size_t ws_size,
                              hipStream_t stream) {
  const float* state_init = (const float*)d_in[0];
  const float* tseq       = (const float*)d_in[1];
  const float* dW1        = (const float*)d_in[2];
  const float* db1        = (const float*)d_in[3];
  const float* dW2        = (const float*)d_in[4];
  const float* db2        = (const float*)d_in[5];
  const float* dW3        = (const float*)d_in[6];
  const float* db3        = (const float*)d_in[7];
  const float* diff_log   = (const float*)d_in[8];
  const float* pW1        = (const float*)d_in[9];
  const float* pb1        = (const float*)d_in[10];
  const float* pW2        = (const float*)d_in[11];
  const float* pb2        = (const float*)d_in[12];
  const float* pW3        = (const float*)d_in[13];
  const float* pb3        = (const float*)d_in[14];
  float* ws = (float*)d_ws;
  unsigned* wsu = (unsigned*)d_ws;

  bool m2 = ws_size >= (size_t)WS_FLOATS_M2 * 4;
  bool m1 = ws_size >= (size_t)WS_FLOATS_M1 * 4;

  key_kernel<<<1, 64, 0, stream>>>(wsu);
  phi_kernel<<<64, 64, 0, stream>>>(tseq, pW1, pb1, pW2, pb2, pW3, pb3, diff_log, ws);
  if (m2) {
    stable_kernel<true><<<4096, 256, 0, stream>>>(wsu, ws);
    sim2_kernel<<<32, 1024, 0, stream>>>(state_init, tseq, dW1, db1, dW2, db2,
                                         dW3, db3, ws, (float*)d_out);
  } else if (m1) {
    stable_kernel<false><<<4096, 256, 0, stream>>>(wsu, ws);
    lk_kernel<<<256, 256, 0, stream>>>(wsu, ws);
    sim_kernel<true><<<32, 1024, 0, stream>>>(state_init, tseq, dW1, db1, dW2, db2,
                                              dW3, db3, ws, wsu, (float*)d_out);
  } else {
    sim_kernel<false><<<32, 1024, 0, stream>>>(state_init, tseq, dW1, db1, dW2, db2,
                                               dW3, db3, ws, wsu, (float*)d_out);
  }
}